// Round 8
// baseline (403.946 us; speedup 1.0000x reference)
//
#include <hip/hip_runtime.h>
#include <cfloat>
#include <cstdint>
#include <cstddef>

using u16 = unsigned short;
typedef __attribute__((ext_vector_type(8))) short short8;
typedef __attribute__((ext_vector_type(4))) float f32x4;

#define HEADS 6
#define NSEQ 4096
#define SCALEF 0.125f
#define LOG2E 1.4426950408889634f
#define SC2 (SCALEF * LOG2E)

#if __has_builtin(__builtin_amdgcn_exp2f)
#define EXP2(x) __builtin_amdgcn_exp2f(x)
#else
#define EXP2(x) exp2f(x)
#endif

__device__ __forceinline__ f32x4 vmin4(f32x4 a, f32x4 b) {
#if __has_builtin(__builtin_elementwise_min)
  return __builtin_elementwise_min(a, b);
#else
  f32x4 r; for (int i = 0; i < 4; ++i) r[i] = fminf(a[i], b[i]); return r;
#endif
}
__device__ __forceinline__ f32x4 vmax4(f32x4 a, f32x4 b) {
#if __has_builtin(__builtin_elementwise_max)
  return __builtin_elementwise_max(a, b);
#else
  f32x4 r; for (int i = 0; i < 4; ++i) r[i] = fmaxf(a[i], b[i]); return r;
#endif
}

__device__ __forceinline__ u16 f2bf_rn(float f) {
  unsigned int u = __builtin_bit_cast(unsigned int, f);
  u = (u + 0x7FFFu + ((u >> 16) & 1u)) >> 16;
  return (u16)u;
}

__device__ __forceinline__ void gload_lds16(const void* g, void* l) {
  __builtin_amdgcn_global_load_lds((const __attribute__((address_space(1))) void*)g,
                                   (__attribute__((address_space(3))) void*)l, 16, 0, 0);
}

// Swizzled b128 read from a [rows][64] u16 LDS tile (128B rows). (GEMM use)
__device__ __forceinline__ short8 frag_read(const u16* tile, int row, int blk) {
  int byt = row * 128 + ((blk * 16) ^ ((row & 7) << 4));
  return *(const short8*)((const char*)tile + byt);
}

__device__ __forceinline__ void cast8(const float* __restrict__ s, u16* __restrict__ d, int i) {
  const float4* sp = (const float4*)s;
  float4 a = sp[2 * i], b = sp[2 * i + 1];
  short8 r;
  r[0] = (short)f2bf_rn(a.x); r[1] = (short)f2bf_rn(a.y);
  r[2] = (short)f2bf_rn(a.z); r[3] = (short)f2bf_rn(a.w);
  r[4] = (short)f2bf_rn(b.x); r[5] = (short)f2bf_rn(b.y);
  r[6] = (short)f2bf_rn(b.z); r[7] = (short)f2bf_rn(b.w);
  ((short8*)d)[i] = r;
}

// fused prep: cast x / w_qkv / w_proj to bf16 + mask -> float addend
__global__ void prep_kernel(const float* __restrict__ x, const float* __restrict__ wqkv,
                            const float* __restrict__ wproj, const int* __restrict__ mask,
                            u16* __restrict__ xb, u16* __restrict__ wqb, u16* __restrict__ wpb,
                            float* __restrict__ madd) {
  const int NX = 3145728 / 8, NQ = 442368 / 8, NP = 147456 / 8;
  int i = blockIdx.x * blockDim.x + threadIdx.x;
  if (i < NX) cast8(x, xb, i);
  else if (i < NX + NQ) cast8(wqkv, wqb, i - NX);
  else if (i < NX + NQ + NP) cast8(wproj, wpb, i - NX - NQ);
  else {
    int j = i - (NX + NQ + NP);
    if (j < 2 * NSEQ) madd[j] = mask[j] ? 0.f : -FLT_MAX;
  }
}

// C = A(MxK) * B(NxK)^T ; 128x128 tile, BK=64, 4 waves (2x2 of 64x64).
template <int EPI>
__launch_bounds__(256)
__global__ void gemm_bt(const u16* __restrict__ A, const u16* __restrict__ B,
                        int Kdim, int Ndim,
                        u16* __restrict__ q_out, u16* __restrict__ k_out, u16* __restrict__ vt_out,
                        const float* __restrict__ bias, float* __restrict__ out) {
  __shared__ u16 lA[128 * 64];
  __shared__ u16 lB[128 * 64];
  int brow = blockIdx.x, bcol = blockIdx.y;
  int tid = threadIdx.x;
  int w = tid >> 6, lane = tid & 63;
  int wr = w >> 1, wc = w & 1;
  int r_in = lane >> 3;
  int jblk = (lane & 7) ^ r_in;
  int l15 = lane & 15, lg = lane >> 4;

  f32x4 acc[4][4];
#pragma unroll
  for (int i = 0; i < 4; i++)
#pragma unroll
    for (int j = 0; j < 4; j++) acc[i][j] = (f32x4){0.f, 0.f, 0.f, 0.f};

  const u16* Ab = A + (size_t)(brow * 128 + w * 32 + r_in) * Kdim + jblk * 8;
  const u16* Bb = B + (size_t)(bcol * 128 + w * 32 + r_in) * Kdim + jblk * 8;

  int ksteps = Kdim >> 6;
  for (int kt = 0; kt < ksteps; ++kt) {
    __syncthreads();
#pragma unroll
    for (int c = 0; c < 4; ++c) {
      gload_lds16(Ab + kt * 64 + (size_t)(c * 8) * Kdim, &lA[(w * 32 + c * 8) * 64]);
      gload_lds16(Bb + kt * 64 + (size_t)(c * 8) * Kdim, &lB[(w * 32 + c * 8) * 64]);
    }
    asm volatile("s_waitcnt vmcnt(0)" ::: "memory");
    __syncthreads();

    short8 af[4][2], bfr[4][2];
#pragma unroll
    for (int ms = 0; ms < 4; ++ms)
#pragma unroll
      for (int hf = 0; hf < 2; ++hf)
        af[ms][hf] = frag_read(lA, wr * 64 + ms * 16 + l15, hf * 4 + lg);
#pragma unroll
    for (int ns = 0; ns < 4; ++ns)
#pragma unroll
      for (int hf = 0; hf < 2; ++hf)
        bfr[ns][hf] = frag_read(lB, wc * 64 + ns * 16 + l15, hf * 4 + lg);
#pragma unroll
    for (int ms = 0; ms < 4; ++ms)
#pragma unroll
      for (int ns = 0; ns < 4; ++ns) {
        acc[ms][ns] = __builtin_amdgcn_mfma_f32_16x16x32_bf16(af[ms][0], bfr[ns][0], acc[ms][ns], 0, 0, 0);
        acc[ms][ns] = __builtin_amdgcn_mfma_f32_16x16x32_bf16(af[ms][1], bfr[ns][1], acc[ms][ns], 0, 0, 0);
      }
  }

#pragma unroll
  for (int ms = 0; ms < 4; ++ms)
#pragma unroll
    for (int ns = 0; ns < 4; ++ns)
#pragma unroll
      for (int r = 0; r < 4; ++r) {
        int row_g = brow * 128 + wr * 64 + ms * 16 + lg * 4 + r;
        int col_g = bcol * 128 + wc * 64 + ns * 16 + l15;
        float v = acc[ms][ns][r];
        if (EPI == 0) {
          int t = col_g / 384;
          int rem = col_g - t * 384;
          int h = rem >> 6, d = rem & 63;
          int b = row_g >> 12, n = row_g & 4095;
          u16 val = f2bf_rn(v);
          size_t bh = (size_t)(b * HEADS + h);
          if (t == 0)      q_out[(bh * NSEQ + n) * 64 + d] = val;
          else if (t == 1) k_out[(bh * NSEQ + n) * 64 + d] = val;
          else             vt_out[(bh * 64 + d) * NSEQ + n] = val;
        } else {
          out[(size_t)row_g * Ndim + col_g] = v + bias[col_g];
        }
      }
}

// Flash attention, zero-LDS zero-barrier: 1 wave per block, 16 q-rows/wave.
// K/V fragments loaded directly from global (L1/L2-resident); operand values
// byte-identical to the R3/R5-proven LDS path. K prefetched one tile ahead.
__launch_bounds__(64, 3)
__global__ void attn_kernel(const u16* __restrict__ qg, const u16* __restrict__ kg,
                            const u16* __restrict__ vtg, const float* __restrict__ madd,
                            u16* __restrict__ attn_out) {
  // bijective XCD swizzle: 3072 blocks, 384 per XCD; consecutive-after-swizzle
  // blocks share bh -> K/V stream L1/L2-hot per XCD
  int bid = blockIdx.x;
  int orig = (bid & 7) * 384 + (bid >> 3);
  int qc = orig & 255, bh = orig >> 8;

  int b = bh / HEADS, hd = bh - b * HEADS;
  int lane = threadIdx.x;
  int l15 = lane & 15, lg = lane >> 4;

  const u16* Q = qg + (size_t)bh * NSEQ * 64;
  const u16* K = kg + (size_t)bh * NSEQ * 64;
  const u16* VT = vtg + (size_t)bh * 64 * NSEQ;
  const float* marow = madd + b * NSEQ;

  int qrow = qc * 16 + l15;
  short8 qf[2];
#pragma unroll
  for (int hf = 0; hf < 2; ++hf)
    qf[hf] = *(const short8*)(Q + (size_t)qrow * 64 + hf * 32 + lg * 8);

  float aqf = marow[qrow];                       // 0 or -FLT_MAX
  f32x4 aqf4 = (f32x4){aqf, aqf, aqf, aqf};

  // per-lane global fragment bases
  const u16* Kl = K + l15 * 64 + lg * 8;         // + t*4096 + cs*1024 + hf*32
  const u16* Vl = VT + (size_t)l15 * NSEQ + lg * 8;  // + ds*16*NSEQ + t*64 + hf*32

  f32x4 acc[4];  // O^T: acc[ds][r] = O[d = ds*16 + lg*4 + r][q = qrow]
#pragma unroll
  for (int ds_ = 0; ds_ < 4; ++ds_) acc[ds_] = (f32x4){0.f, 0.f, 0.f, 0.f};
  float m2 = -INFINITY, l_r = 0.f;

  // prologue: K fragments of tile 0
  short8 kf[4][2];
#pragma unroll
  for (int cs = 0; cs < 4; ++cs)
#pragma unroll
    for (int hf = 0; hf < 2; ++hf)
      kf[cs][hf] = *(const short8*)(Kl + cs * 1024 + hf * 32);

  const int NT = NSEQ / 64;
  for (int t = 0; t < NT; ++t) {
    int k0 = t * 64;

    // V fragments of tile t (latency hidden under QK + softmax)
    short8 vf[4][2];
#pragma unroll
    for (int ds_ = 0; ds_ < 4; ++ds_)
#pragma unroll
      for (int hf = 0; hf < 2; ++hf)
        vf[ds_][hf] = *(const short8*)(Vl + (size_t)(ds_ * 16) * NSEQ + k0 + hf * 32);

    // S^T = K Q^T : p[cs][r] = S[q = qrow][k = k0 + cs*16 + lg*4 + r]
    f32x4 p[4];
    __builtin_amdgcn_s_setprio(1);
#pragma unroll
    for (int cs = 0; cs < 4; ++cs) {
      f32x4 z = (f32x4){0.f, 0.f, 0.f, 0.f};
      z = __builtin_amdgcn_mfma_f32_16x16x32_bf16(kf[cs][0], qf[0], z, 0, 0, 0);
      p[cs] = __builtin_amdgcn_mfma_f32_16x16x32_bf16(kf[cs][1], qf[1], z, 0, 0, 0);
    }
    __builtin_amdgcn_s_setprio(0);

    // prefetch K fragments of tile t+1 (consumed next iter; hidden under softmax+PV)
    if (t + 1 < NT) {
#pragma unroll
      for (int cs = 0; cs < 4; ++cs)
#pragma unroll
        for (int hf = 0; hf < 2; ++hf)
          kf[cs][hf] = *(const short8*)(Kl + (size_t)(t + 1) * 4096 + cs * 1024 + hf * 32);
    }

    // log2-space pre-softmax with inline mask addend
#pragma unroll
    for (int cs = 0; cs < 4; ++cs) {
      f32x4 mf = *(const f32x4*)(marow + k0 + cs * 16 + lg * 4);
      p[cs] = p[cs] * SC2 + vmin4(mf, aqf4);
    }

    // row max + 2 shuffles
    f32x4 t4 = vmax4(vmax4(p[0], p[1]), vmax4(p[2], p[3]));
    float tm = fmaxf(fmaxf(t4[0], t4[1]), fmaxf(t4[2], t4[3]));
    tm = fmaxf(tm, __shfl_xor(tm, 16));
    tm = fmaxf(tm, __shfl_xor(tm, 32));

    // T13 defer-rescale (THR=8)
    if (!__all(tm <= m2 + 8.0f)) {
      float mnew = fmaxf(m2, tm);
      float corr = EXP2(m2 - mnew);
      m2 = mnew;
      l_r *= corr;
#pragma unroll
      for (int ds_ = 0; ds_ < 4; ++ds_) acc[ds_] *= corr;
    }

    // p = exp2(p - m2)
#pragma unroll
    for (int cs = 0; cs < 4; ++cs) {
      f32x4 d = p[cs] - m2;
#pragma unroll
      for (int r = 0; r < 4; ++r) p[cs][r] = EXP2(d[r]);
    }
    f32x4 s4 = (p[0] + p[1]) + (p[2] + p[3]);
    float rsum = (s4[0] + s4[1]) + (s4[2] + s4[3]);
    rsum += __shfl_xor(rsum, 16);
    rsum += __shfl_xor(rsum, 32);
    l_r += rsum;

    // P^T -> bf16 packed words
    uint32_t wd[4][2];
#pragma unroll
    for (int cs = 0; cs < 4; ++cs)
#pragma unroll
      for (int hh = 0; hh < 2; ++hh)
        asm("v_cvt_pk_bf16_f32 %0, %1, %2" : "=v"(wd[cs][hh]) : "v"(p[cs][2 * hh]), "v"(p[cs][2 * hh + 1]));

    // permlane dance -> PV B-operand fragments (2 chunks of 32 k)
    short8 pf[2];
#pragma unroll
    for (int c = 0; c < 2; ++c) {
      union { uint32_t u[4]; short8 s8; } cv;
#pragma unroll
      for (int hh = 0; hh < 2; ++hh) {
        uint32_t A = wd[2 * c][hh], B = wd[2 * c + 1][hh];
        asm("v_permlane32_swap_b32 %0, %1" : "+v"(A), "+v"(B));
        asm("v_permlane16_swap_b32 %0, %1" : "+v"(A), "+v"(B));
        cv.u[hh] = A;
        cv.u[2 + hh] = B;
      }
      pf[c] = cv.s8;
    }

    // O^T += V^T P^T
    __builtin_amdgcn_s_setprio(1);
#pragma unroll
    for (int ds_ = 0; ds_ < 4; ++ds_) {
      acc[ds_] = __builtin_amdgcn_mfma_f32_16x16x32_bf16(vf[ds_][0], pf[0], acc[ds_], 0, 0, 0);
      acc[ds_] = __builtin_amdgcn_mfma_f32_16x16x32_bf16(vf[ds_][1], pf[1], acc[ds_], 0, 0, 0);
    }
    __builtin_amdgcn_s_setprio(0);
  }

  // epilogue: attn_out[b, n=qrow, hd*64 + d] = O^T[d][qrow] / l
  float inv = 1.0f / l_r;
  size_t base = ((size_t)b * NSEQ + qrow) * 384 + hd * 64;
#pragma unroll
  for (int ds_ = 0; ds_ < 4; ++ds_) {
    uint32_t w0, w1;
    float a0 = acc[ds_][0] * inv, a1 = acc[ds_][1] * inv;
    float a2 = acc[ds_][2] * inv, a3 = acc[ds_][3] * inv;
    asm("v_cvt_pk_bf16_f32 %0, %1, %2" : "=v"(w0) : "v"(a0), "v"(a1));
    asm("v_cvt_pk_bf16_f32 %0, %1, %2" : "=v"(w1) : "v"(a2), "v"(a3));
    uint2 st; st.x = w0; st.y = w1;
    *(uint2*)(attn_out + base + ds_ * 16 + lg * 4) = st;
  }
}

extern "C" void kernel_launch(void* const* d_in, const int* in_sizes, int n_in,
                              void* d_out, int out_size, void* d_ws, size_t ws_size,
                              hipStream_t stream) {
  const float* x = (const float*)d_in[0];
  const int* mask = (const int*)d_in[1];
  const float* w_qkv = (const float*)d_in[2];
  const float* w_proj = (const float*)d_in[3];
  const float* b_proj = (const float*)d_in[4];
  float* out = (float*)d_out;

  char* ws = (char*)d_ws;
  u16* x_bf = (u16*)(ws + 0);              //  8192x384
  u16* wqkv_bf = (u16*)(ws + 6291456);     //  1152x384
  u16* wproj_bf = (u16*)(ws + 7176192);    //   384x384
  u16* q_bf = (u16*)(ws + 7471104);        //  [b,h,n,d]
  u16* k_bf = (u16*)(ws + 13762560);       //  [b,h,n,d]
  u16* vt_bf = (u16*)(ws + 20054016);      //  [b,h,d,n]
  u16* attn_bf = (u16*)(ws + 26345472);    //  8192x384
  float* madd = (float*)(ws + 32636928);   //  [2][4096] f32

  // fused prep: 3 casts + mask addend
  const int NPREP = 3145728 / 8 + 442368 / 8 + 147456 / 8 + 2 * NSEQ;
  prep_kernel<<<(NPREP + 255) / 256, 256, 0, stream>>>(x, w_qkv, w_proj, mask,
                                                       x_bf, wqkv_bf, wproj_bf, madd);

  gemm_bt<0><<<dim3(64, 9), 256, 0, stream>>>(x_bf, wqkv_bf, 384, 1152,
                                              q_bf, k_bf, vt_bf, nullptr, nullptr);
  attn_kernel<<<3072, 64, 0, stream>>>(q_bf, k_bf, vt_bf, madd, attn_bf);
  gemm_bt<1><<<dim3(64, 3), 256, 0, stream>>>(attn_bf, wproj_bf, 384, 384,
                                              nullptr, nullptr, nullptr, b_proj, out);
}

// Round 9
// 170.570 us; speedup vs baseline: 2.3682x; 2.3682x over previous
//
#include <hip/hip_runtime.h>
#include <cfloat>
#include <cstdint>
#include <cstddef>

using u16 = unsigned short;
typedef __attribute__((ext_vector_type(8))) short short8;
typedef __attribute__((ext_vector_type(4))) float f32x4;

#define HEADS 6
#define NSEQ 4096
#define SCALEF 0.125f
#define LOG2E 1.4426950408889634f
#define SC2 (SCALEF * LOG2E)

#if __has_builtin(__builtin_amdgcn_exp2f)
#define EXP2(x) __builtin_amdgcn_exp2f(x)
#else
#define EXP2(x) exp2f(x)
#endif

__device__ __forceinline__ f32x4 vmin4(f32x4 a, f32x4 b) {
#if __has_builtin(__builtin_elementwise_min)
  return __builtin_elementwise_min(a, b);
#else
  f32x4 r; for (int i = 0; i < 4; ++i) r[i] = fminf(a[i], b[i]); return r;
#endif
}
__device__ __forceinline__ f32x4 vmax4(f32x4 a, f32x4 b) {
#if __has_builtin(__builtin_elementwise_max)
  return __builtin_elementwise_max(a, b);
#else
  f32x4 r; for (int i = 0; i < 4; ++i) r[i] = fmaxf(a[i], b[i]); return r;
#endif
}

__device__ __forceinline__ u16 f2bf_rn(float f) {
  unsigned int u = __builtin_bit_cast(unsigned int, f);
  u = (u + 0x7FFFu + ((u >> 16) & 1u)) >> 16;
  return (u16)u;
}

__device__ __forceinline__ void gload_lds16(const void* g, void* l) {
  __builtin_amdgcn_global_load_lds((const __attribute__((address_space(1))) void*)g,
                                   (__attribute__((address_space(3))) void*)l, 16, 0, 0);
}

// Swizzled b128 read from a [rows][64] u16 LDS tile (128B rows). (GEMM use)
__device__ __forceinline__ short8 frag_read(const u16* tile, int row, int blk) {
  int byt = row * 128 + ((blk * 16) ^ ((row & 7) << 4));
  return *(const short8*)((const char*)tile + byt);
}

__device__ __forceinline__ void cast8(const float* __restrict__ s, u16* __restrict__ d, int i) {
  const float4* sp = (const float4*)s;
  float4 a = sp[2 * i], b = sp[2 * i + 1];
  short8 r;
  r[0] = (short)f2bf_rn(a.x); r[1] = (short)f2bf_rn(a.y);
  r[2] = (short)f2bf_rn(a.z); r[3] = (short)f2bf_rn(a.w);
  r[4] = (short)f2bf_rn(b.x); r[5] = (short)f2bf_rn(b.y);
  r[6] = (short)f2bf_rn(b.z); r[7] = (short)f2bf_rn(b.w);
  ((short8*)d)[i] = r;
}

// fused prep: cast x / w_qkv / w_proj to bf16 + mask -> float addend
__global__ void prep_kernel(const float* __restrict__ x, const float* __restrict__ wqkv,
                            const float* __restrict__ wproj, const int* __restrict__ mask,
                            u16* __restrict__ xb, u16* __restrict__ wqb, u16* __restrict__ wpb,
                            float* __restrict__ madd) {
  const int NX = 3145728 / 8, NQ = 442368 / 8, NP = 147456 / 8;
  int i = blockIdx.x * blockDim.x + threadIdx.x;
  if (i < NX) cast8(x, xb, i);
  else if (i < NX + NQ) cast8(wqkv, wqb, i - NX);
  else if (i < NX + NQ + NP) cast8(wproj, wpb, i - NX - NQ);
  else {
    int j = i - (NX + NQ + NP);
    if (j < 2 * NSEQ) madd[j] = mask[j] ? 0.f : -FLT_MAX;
  }
}

// C = A(MxK) * B(NxK)^T ; 128x128 tile, BK=64, 4 waves (2x2 of 64x64).
template <int EPI>
__launch_bounds__(256)
__global__ void gemm_bt(const u16* __restrict__ A, const u16* __restrict__ B,
                        int Kdim, int Ndim,
                        u16* __restrict__ q_out, u16* __restrict__ k_out, u16* __restrict__ vt_out,
                        const float* __restrict__ bias, float* __restrict__ out) {
  __shared__ u16 lA[128 * 64];
  __shared__ u16 lB[128 * 64];
  int brow = blockIdx.x, bcol = blockIdx.y;
  int tid = threadIdx.x;
  int w = tid >> 6, lane = tid & 63;
  int wr = w >> 1, wc = w & 1;
  int r_in = lane >> 3;
  int jblk = (lane & 7) ^ r_in;
  int l15 = lane & 15, lg = lane >> 4;

  f32x4 acc[4][4];
#pragma unroll
  for (int i = 0; i < 4; i++)
#pragma unroll
    for (int j = 0; j < 4; j++) acc[i][j] = (f32x4){0.f, 0.f, 0.f, 0.f};

  const u16* Ab = A + (size_t)(brow * 128 + w * 32 + r_in) * Kdim + jblk * 8;
  const u16* Bb = B + (size_t)(bcol * 128 + w * 32 + r_in) * Kdim + jblk * 8;

  int ksteps = Kdim >> 6;
  for (int kt = 0; kt < ksteps; ++kt) {
    __syncthreads();
#pragma unroll
    for (int c = 0; c < 4; ++c) {
      gload_lds16(Ab + kt * 64 + (size_t)(c * 8) * Kdim, &lA[(w * 32 + c * 8) * 64]);
      gload_lds16(Bb + kt * 64 + (size_t)(c * 8) * Kdim, &lB[(w * 32 + c * 8) * 64]);
    }
    asm volatile("s_waitcnt vmcnt(0)" ::: "memory");
    __syncthreads();

    short8 af[4][2], bfr[4][2];
#pragma unroll
    for (int ms = 0; ms < 4; ++ms)
#pragma unroll
      for (int hf = 0; hf < 2; ++hf)
        af[ms][hf] = frag_read(lA, wr * 64 + ms * 16 + l15, hf * 4 + lg);
#pragma unroll
    for (int ns = 0; ns < 4; ++ns)
#pragma unroll
      for (int hf = 0; hf < 2; ++hf)
        bfr[ns][hf] = frag_read(lB, wc * 64 + ns * 16 + l15, hf * 4 + lg);
#pragma unroll
    for (int ms = 0; ms < 4; ++ms)
#pragma unroll
      for (int ns = 0; ns < 4; ++ns) {
        acc[ms][ns] = __builtin_amdgcn_mfma_f32_16x16x32_bf16(af[ms][0], bfr[ns][0], acc[ms][ns], 0, 0, 0);
        acc[ms][ns] = __builtin_amdgcn_mfma_f32_16x16x32_bf16(af[ms][1], bfr[ns][1], acc[ms][ns], 0, 0, 0);
      }
  }

#pragma unroll
  for (int ms = 0; ms < 4; ++ms)
#pragma unroll
    for (int ns = 0; ns < 4; ++ns)
#pragma unroll
      for (int r = 0; r < 4; ++r) {
        int row_g = brow * 128 + wr * 64 + ms * 16 + lg * 4 + r;
        int col_g = bcol * 128 + wc * 64 + ns * 16 + l15;
        float v = acc[ms][ns][r];
        if (EPI == 0) {
          int t = col_g / 384;
          int rem = col_g - t * 384;
          int h = rem >> 6, d = rem & 63;
          int b = row_g >> 12, n = row_g & 4095;
          u16 val = f2bf_rn(v);
          size_t bh = (size_t)(b * HEADS + h);
          if (t == 0)      q_out[(bh * NSEQ + n) * 64 + d] = val;
          else if (t == 1) k_out[(bh * NSEQ + n) * 64 + d] = val;
          else             vt_out[(bh * 64 + d) * NSEQ + n] = val;
        } else {
          out[(size_t)row_g * Ndim + col_g] = v + bias[col_g];
        }
      }
}

// Flash attention, swapped-operand, QBLK=32 per wave:
// 256 thr = 4 waves = 2 q-groups (32 q-rows each) x 2 k-halves (2048 k each).
// Each wave's 8 kf + 8 vf LDS reads feed 2 q-subtiles (DS traffic per work halved).
// R5-proven single-buffer sync; R6-style padded LDS merge of the k-halves.
__launch_bounds__(256, 3)
__global__ void attn_kernel(const u16* __restrict__ qg, const u16* __restrict__ kg,
                            const u16* __restrict__ vtg, const float* __restrict__ madd,
                            u16* __restrict__ attn_out) {
  __shared__ __align__(16) char smem[32768];  // [kh][ lK 8KB | lV 8KB ]; reused for merge

  // bijective XCD swizzle: 768 blocks, 96 per XCD
  int bid = blockIdx.y * 64 + blockIdx.x;
  int orig = (bid & 7) * 96 + (bid >> 3);
  int qb = orig & 63, bh = orig >> 6;

  int b = bh / HEADS, hd = bh - b * HEADS;
  int q0 = qb * 64;
  int tid = threadIdx.x;
  int w = tid >> 6, lane = tid & 63;
  int g = w >> 1, kh = w & 1;          // q-group, k-half
  int l15 = lane & 15, lg = lane >> 4;
  int r_in = lane >> 3, jblk = (lane & 7) ^ r_in;

  u16* lK = (u16*)(smem + kh * 16384);
  u16* lV = (u16*)(smem + kh * 16384 + 8192);

  const u16* Q = qg + (size_t)bh * NSEQ * 64;
  const u16* K = kg + (size_t)bh * NSEQ * 64;
  const u16* VT = vtg + (size_t)bh * 64 * NSEQ;
  const float* marow = madd + b * NSEQ;

  // two q-subtiles per wave: qrow[qs] = q0 + g*32 + qs*16 + l15
  short8 qf[2][2];
  f32x4 aqf4[2];
#pragma unroll
  for (int qs = 0; qs < 2; ++qs) {
    int qrow = q0 + g * 32 + qs * 16 + l15;
#pragma unroll
    for (int hf = 0; hf < 2; ++hf)
      qf[qs][hf] = *(const short8*)(Q + (size_t)qrow * 64 + hf * 32 + lg * 8);
    float a = marow[qrow];
    aqf4[qs] = (f32x4){a, a, a, a};
  }

  // lane-constant swizzled read offsets (row = x*16 + l15 -> row&7 == l15&7)
  int swk = (l15 & 7) << 4;
  int offKA = l15 * 128 + ((lg * 16) ^ swk);
  int offKB = l15 * 128 + (((4 + lg) * 16) ^ swk);

  f32x4 acc[2][4];  // acc[qs][ds][r] = O[d = ds*16+lg*4+r][q = qrow(qs)]
#pragma unroll
  for (int qs = 0; qs < 2; ++qs)
#pragma unroll
    for (int ds_ = 0; ds_ < 4; ++ds_) acc[qs][ds_] = (f32x4){0.f, 0.f, 0.f, 0.f};
  float m2[2] = {-INFINITY, -INFINITY}, l2[2] = {0.f, 0.f};

  int kbase = kh * (NSEQ / 2);

  // STAGE: the 2 waves of each k-half cooperatively fill their lK/lV
  // (wave g: rows g*32+c*8, c=0..3) — proven linear-dest/pre-swizzled-source.
#define STAGE(k0s)                                                                      \
  {                                                                                     \
    _Pragma("unroll")                                                                   \
    for (int c = 0; c < 4; ++c) {                                                       \
      int rowb = g * 32 + c * 8;                                                        \
      gload_lds16(K + (size_t)((k0s) + rowb + r_in) * 64 + jblk * 8, &lK[rowb * 64]);   \
      gload_lds16(VT + (size_t)(rowb + r_in) * NSEQ + (k0s) + jblk * 8, &lV[rowb * 64]);\
    }                                                                                   \
  }

  STAGE(kbase);
  asm volatile("s_waitcnt vmcnt(0)" ::: "memory");
  __syncthreads();

  const int NT2 = (NSEQ / 2) / 64;   // 32 tiles per half
  for (int t = 0; t < NT2; ++t) {
    int k0 = kbase + t * 64;

    // S^T = K Q^T for both q-subtiles; kf reads shared across qs
    f32x4 p[2][4];
    __builtin_amdgcn_s_setprio(1);
#pragma unroll
    for (int cs = 0; cs < 4; ++cs) {
      short8 kf0 = *(const short8*)((const char*)lK + offKA + cs * 2048);
      short8 kf1 = *(const short8*)((const char*)lK + offKB + cs * 2048);
#pragma unroll
      for (int qs = 0; qs < 2; ++qs) {
        f32x4 z = (f32x4){0.f, 0.f, 0.f, 0.f};
        z = __builtin_amdgcn_mfma_f32_16x16x32_bf16(kf0, qf[qs][0], z, 0, 0, 0);
        p[qs][cs] = __builtin_amdgcn_mfma_f32_16x16x32_bf16(kf1, qf[qs][1], z, 0, 0, 0);
      }
    }
    __builtin_amdgcn_s_setprio(0);

    // V fragments once, reused by both q-subtiles
    short8 vf0[4], vf1[4];
#pragma unroll
    for (int ds_ = 0; ds_ < 4; ++ds_) {
      vf0[ds_] = *(const short8*)((const char*)lV + offKA + ds_ * 2048);
      vf1[ds_] = *(const short8*)((const char*)lV + offKB + ds_ * 2048);
    }

    // mask addends shared across qs
    f32x4 mf[4];
#pragma unroll
    for (int cs = 0; cs < 4; ++cs)
      mf[cs] = *(const f32x4*)(marow + k0 + cs * 16 + lg * 4);

    short8 pf[2][2];
#pragma unroll
    for (int qs = 0; qs < 2; ++qs) {
#pragma unroll
      for (int cs = 0; cs < 4; ++cs)
        p[qs][cs] = p[qs][cs] * SC2 + vmin4(mf[cs], aqf4[qs]);

      f32x4 t4 = vmax4(vmax4(p[qs][0], p[qs][1]), vmax4(p[qs][2], p[qs][3]));
      float tm = fmaxf(fmaxf(t4[0], t4[1]), fmaxf(t4[2], t4[3]));
      tm = fmaxf(tm, __shfl_xor(tm, 16));
      tm = fmaxf(tm, __shfl_xor(tm, 32));

      if (!__all(tm <= m2[qs] + 8.0f)) {
        float mnew = fmaxf(m2[qs], tm);
        float corr = EXP2(m2[qs] - mnew);
        m2[qs] = mnew;
        l2[qs] *= corr;
#pragma unroll
        for (int ds_ = 0; ds_ < 4; ++ds_) acc[qs][ds_] *= corr;
      }

#pragma unroll
      for (int cs = 0; cs < 4; ++cs) {
        f32x4 d = p[qs][cs] - m2[qs];
#pragma unroll
        for (int r = 0; r < 4; ++r) p[qs][cs][r] = EXP2(d[r]);
      }
      f32x4 s4 = (p[qs][0] + p[qs][1]) + (p[qs][2] + p[qs][3]);
      float rsum = (s4[0] + s4[1]) + (s4[2] + s4[3]);
      rsum += __shfl_xor(rsum, 16);
      rsum += __shfl_xor(rsum, 32);
      l2[qs] += rsum;

      // P^T -> bf16 words -> permlane dance -> PV B-fragments
      uint32_t wd[4][2];
#pragma unroll
      for (int cs = 0; cs < 4; ++cs)
#pragma unroll
        for (int hh = 0; hh < 2; ++hh)
          asm("v_cvt_pk_bf16_f32 %0, %1, %2" : "=v"(wd[cs][hh]) : "v"(p[qs][cs][2 * hh]), "v"(p[qs][cs][2 * hh + 1]));
#pragma unroll
      for (int c = 0; c < 2; ++c) {
        union { uint32_t u[4]; short8 s8; } cv;
#pragma unroll
        for (int hh = 0; hh < 2; ++hh) {
          uint32_t A = wd[2 * c][hh], B = wd[2 * c + 1][hh];
          asm("v_permlane32_swap_b32 %0, %1" : "+v"(A), "+v"(B));
          asm("v_permlane16_swap_b32 %0, %1" : "+v"(A), "+v"(B));
          cv.u[hh] = A;
          cv.u[2 + hh] = B;
        }
        pf[qs][c] = cv.s8;
      }
    }

    // O^T += V^T P^T  (vf shared across qs)
    __builtin_amdgcn_s_setprio(1);
#pragma unroll
    for (int ds_ = 0; ds_ < 4; ++ds_)
#pragma unroll
      for (int qs = 0; qs < 2; ++qs) {
        acc[qs][ds_] = __builtin_amdgcn_mfma_f32_16x16x32_bf16(vf0[ds_], pf[qs][0], acc[qs][ds_], 0, 0, 0);
        acc[qs][ds_] = __builtin_amdgcn_mfma_f32_16x16x32_bf16(vf1[ds_], pf[qs][1], acc[qs][ds_], 0, 0, 0);
      }
    __builtin_amdgcn_s_setprio(0);

    __syncthreads();                  // all waves done reading tile t
    if (t + 1 < NT2) {
      STAGE(k0 + 64);
      asm volatile("s_waitcnt vmcnt(0)" ::: "memory");
      __syncthreads();
    }
  }

  // ---- merge k-halves via LDS (staging dead now) ----
  float* mo = (float*)smem;                 // [4 = g*2+qs][64 d][17] f32
  float* ml = (float*)(smem + 17408);       // [4][16 q][2]

  if (kh == 1) {
#pragma unroll
    for (int qs = 0; qs < 2; ++qs) {
      float* base = mo + (g * 2 + qs) * (64 * 17);
#pragma unroll
      for (int ds_ = 0; ds_ < 4; ++ds_)
#pragma unroll
        for (int r = 0; r < 4; ++r)
          base[(ds_ * 16 + lg * 4 + r) * 17 + l15] = acc[qs][ds_][r];
      if (lg == 0) {
        ml[((g * 2 + qs) * 16 + l15) * 2] = m2[qs];
        ml[((g * 2 + qs) * 16 + l15) * 2 + 1] = l2[qs];
      }
    }
  }
  __syncthreads();
  if (kh == 0) {
#pragma unroll
    for (int qs = 0; qs < 2; ++qs) {
      int qrow = q0 + g * 32 + qs * 16 + l15;
      float m1v = ml[((g * 2 + qs) * 16 + l15) * 2];
      float l1v = ml[((g * 2 + qs) * 16 + l15) * 2 + 1];
      float M = fmaxf(m2[qs], m1v);
      float c0 = EXP2(m2[qs] - M), c1 = EXP2(m1v - M);
      float invL = 1.0f / (l2[qs] * c0 + l1v * c1);
      const float* base = mo + (g * 2 + qs) * (64 * 17);
      size_t obase = ((size_t)b * NSEQ + qrow) * 384 + hd * 64;
#pragma unroll
      for (int ds_ = 0; ds_ < 4; ++ds_) {
        f32x4 ov;
#pragma unroll
        for (int r = 0; r < 4; ++r) ov[r] = base[(ds_ * 16 + lg * 4 + r) * 17 + l15];
        float a0 = (acc[qs][ds_][0] * c0 + ov[0] * c1) * invL;
        float a1 = (acc[qs][ds_][1] * c0 + ov[1] * c1) * invL;
        float a2 = (acc[qs][ds_][2] * c0 + ov[2] * c1) * invL;
        float a3 = (acc[qs][ds_][3] * c0 + ov[3] * c1) * invL;
        uint32_t w0, w1;
        asm("v_cvt_pk_bf16_f32 %0, %1, %2" : "=v"(w0) : "v"(a0), "v"(a1));
        asm("v_cvt_pk_bf16_f32 %0, %1, %2" : "=v"(w1) : "v"(a2), "v"(a3));
        uint2 st; st.x = w0; st.y = w1;
        *(uint2*)(attn_out + obase + ds_ * 16 + lg * 4) = st;
      }
    }
  }
#undef STAGE
}

extern "C" void kernel_launch(void* const* d_in, const int* in_sizes, int n_in,
                              void* d_out, int out_size, void* d_ws, size_t ws_size,
                              hipStream_t stream) {
  const float* x = (const float*)d_in[0];
  const int* mask = (const int*)d_in[1];
  const float* w_qkv = (const float*)d_in[2];
  const float* w_proj = (const float*)d_in[3];
  const float* b_proj = (const float*)d_in[4];
  float* out = (float*)d_out;

  char* ws = (char*)d_ws;
  u16* x_bf = (u16*)(ws + 0);              //  8192x384
  u16* wqkv_bf = (u16*)(ws + 6291456);     //  1152x384
  u16* wproj_bf = (u16*)(ws + 7176192);    //   384x384
  u16* q_bf = (u16*)(ws + 7471104);        //  [b,h,n,d]
  u16* k_bf = (u16*)(ws + 13762560);       //  [b,h,n,d]
  u16* vt_bf = (u16*)(ws + 20054016);      //  [b,h,d,n]
  u16* attn_bf = (u16*)(ws + 26345472);    //  8192x384
  float* madd = (float*)(ws + 32636928);   //  [2][4096] f32

  // fused prep: 3 casts + mask addend
  const int NPREP = 3145728 / 8 + 442368 / 8 + 147456 / 8 + 2 * NSEQ;
  prep_kernel<<<(NPREP + 255) / 256, 256, 0, stream>>>(x, w_qkv, w_proj, mask,
                                                       x_bf, wqkv_bf, wproj_bf, madd);

  gemm_bt<0><<<dim3(64, 9), 256, 0, stream>>>(x_bf, wqkv_bf, 384, 1152,
                                              q_bf, k_bf, vt_bf, nullptr, nullptr);
  attn_kernel<<<dim3(64, 12), 256, 0, stream>>>(q_bf, k_bf, vt_bf, madd, attn_bf);
  gemm_bt<1><<<dim3(64, 3), 256, 0, stream>>>(attn_bf, wproj_bf, 384, 384,
                                              nullptr, nullptr, nullptr, b_proj, out);
}

// Round 10
// 136.946 us; speedup vs baseline: 2.9497x; 1.2455x over previous
//
#include <hip/hip_runtime.h>
#include <cfloat>
#include <cstdint>
#include <cstddef>

using u16 = unsigned short;
typedef __attribute__((ext_vector_type(8))) short short8;
typedef __attribute__((ext_vector_type(4))) float f32x4;

#define HEADS 6
#define NSEQ 4096
#define SCALEF 0.125f
#define LOG2E 1.4426950408889634f
#define SC2 (SCALEF * LOG2E)

#if __has_builtin(__builtin_amdgcn_exp2f)
#define EXP2(x) __builtin_amdgcn_exp2f(x)
#else
#define EXP2(x) exp2f(x)
#endif

__device__ __forceinline__ u16 f2bf_rn(float f) {
  unsigned int u = __builtin_bit_cast(unsigned int, f);
  u = (u + 0x7FFFu + ((u >> 16) & 1u)) >> 16;
  return (u16)u;
}

__device__ __forceinline__ void gload_lds16(const void* g, void* l) {
  __builtin_amdgcn_global_load_lds((const __attribute__((address_space(1))) void*)g,
                                   (__attribute__((address_space(3))) void*)l, 16, 0, 0);
}

// Swizzled b128 read from a [rows][64] u16 LDS tile (128B rows). (GEMM use)
__device__ __forceinline__ short8 frag_read(const u16* tile, int row, int blk) {
  int byt = row * 128 + ((blk * 16) ^ ((row & 7) << 4));
  return *(const short8*)((const char*)tile + byt);
}

__device__ __forceinline__ void cast8(const float* __restrict__ s, u16* __restrict__ d, int i) {
  const float4* sp = (const float4*)s;
  float4 a = sp[2 * i], b = sp[2 * i + 1];
  short8 r;
  r[0] = (short)f2bf_rn(a.x); r[1] = (short)f2bf_rn(a.y);
  r[2] = (short)f2bf_rn(a.z); r[3] = (short)f2bf_rn(a.w);
  r[4] = (short)f2bf_rn(b.x); r[5] = (short)f2bf_rn(b.y);
  r[6] = (short)f2bf_rn(b.z); r[7] = (short)f2bf_rn(b.w);
  ((short8*)d)[i] = r;
}

// fused prep: cast x / w_qkv / w_proj to bf16 + mask -> float addend
__global__ void prep_kernel(const float* __restrict__ x, const float* __restrict__ wqkv,
                            const float* __restrict__ wproj, const int* __restrict__ mask,
                            u16* __restrict__ xb, u16* __restrict__ wqb, u16* __restrict__ wpb,
                            float* __restrict__ madd) {
  const int NX = 3145728 / 8, NQ = 442368 / 8, NP = 147456 / 8;
  int i = blockIdx.x * blockDim.x + threadIdx.x;
  if (i < NX) cast8(x, xb, i);
  else if (i < NX + NQ) cast8(wqkv, wqb, i - NX);
  else if (i < NX + NQ + NP) cast8(wproj, wpb, i - NX - NQ);
  else {
    int j = i - (NX + NQ + NP);
    if (j < 2 * NSEQ) madd[j] = mask[j] ? 0.f : -FLT_MAX;
  }
}

// C = A(MxK) * B(NxK)^T ; 128x128 tile, BK=64, 4 waves (2x2 of 64x64).
template <int EPI>
__launch_bounds__(256)
__global__ void gemm_bt(const u16* __restrict__ A, const u16* __restrict__ B,
                        int Kdim, int Ndim,
                        u16* __restrict__ q_out, u16* __restrict__ k_out, u16* __restrict__ vt_out,
                        const float* __restrict__ bias, float* __restrict__ out) {
  __shared__ u16 lA[128 * 64];
  __shared__ u16 lB[128 * 64];
  int brow = blockIdx.x, bcol = blockIdx.y;
  int tid = threadIdx.x;
  int w = tid >> 6, lane = tid & 63;
  int wr = w >> 1, wc = w & 1;
  int r_in = lane >> 3;
  int jblk = (lane & 7) ^ r_in;
  int l15 = lane & 15, lg = lane >> 4;

  f32x4 acc[4][4];
#pragma unroll
  for (int i = 0; i < 4; i++)
#pragma unroll
    for (int j = 0; j < 4; j++) acc[i][j] = (f32x4){0.f, 0.f, 0.f, 0.f};

  const u16* Ab = A + (size_t)(brow * 128 + w * 32 + r_in) * Kdim + jblk * 8;
  const u16* Bb = B + (size_t)(bcol * 128 + w * 32 + r_in) * Kdim + jblk * 8;

  int ksteps = Kdim >> 6;
  for (int kt = 0; kt < ksteps; ++kt) {
    __syncthreads();
#pragma unroll
    for (int c = 0; c < 4; ++c) {
      gload_lds16(Ab + kt * 64 + (size_t)(c * 8) * Kdim, &lA[(w * 32 + c * 8) * 64]);
      gload_lds16(Bb + kt * 64 + (size_t)(c * 8) * Kdim, &lB[(w * 32 + c * 8) * 64]);
    }
    asm volatile("s_waitcnt vmcnt(0)" ::: "memory");
    __syncthreads();

    short8 af[4][2], bfr[4][2];
#pragma unroll
    for (int ms = 0; ms < 4; ++ms)
#pragma unroll
      for (int hf = 0; hf < 2; ++hf)
        af[ms][hf] = frag_read(lA, wr * 64 + ms * 16 + l15, hf * 4 + lg);
#pragma unroll
    for (int ns = 0; ns < 4; ++ns)
#pragma unroll
      for (int hf = 0; hf < 2; ++hf)
        bfr[ns][hf] = frag_read(lB, wc * 64 + ns * 16 + l15, hf * 4 + lg);
#pragma unroll
    for (int ms = 0; ms < 4; ++ms)
#pragma unroll
      for (int ns = 0; ns < 4; ++ns) {
        acc[ms][ns] = __builtin_amdgcn_mfma_f32_16x16x32_bf16(af[ms][0], bfr[ns][0], acc[ms][ns], 0, 0, 0);
        acc[ms][ns] = __builtin_amdgcn_mfma_f32_16x16x32_bf16(af[ms][1], bfr[ns][1], acc[ms][ns], 0, 0, 0);
      }
  }

#pragma unroll
  for (int ms = 0; ms < 4; ++ms)
#pragma unroll
    for (int ns = 0; ns < 4; ++ns)
#pragma unroll
      for (int r = 0; r < 4; ++r) {
        int row_g = brow * 128 + wr * 64 + ms * 16 + lg * 4 + r;
        int col_g = bcol * 128 + wc * 64 + ns * 16 + l15;
        float v = acc[ms][ns][r];
        if (EPI == 0) {
          int t = col_g / 384;
          int rem = col_g - t * 384;
          int h = rem >> 6, d = rem & 63;
          int b = row_g >> 12, n = row_g & 4095;
          u16 val = f2bf_rn(v);
          size_t bh = (size_t)(b * HEADS + h);
          if (t == 0)      q_out[(bh * NSEQ + n) * 64 + d] = val;
          else if (t == 1) k_out[(bh * NSEQ + n) * 64 + d] = val;
          else             vt_out[(bh * 64 + d) * NSEQ + n] = val;
        } else {
          out[(size_t)row_g * Ndim + col_g] = v + bias[col_g];
        }
      }
}

// Flash attention, swapped-operand, KT=128, single 32KB buffer (R5-proven core).
// STREAMING softmax: p = exp2(fma(s, scq, mf*qsel)) — no running max, no per-tile
// shuffles, no rescale. Per-lane partial l reduced once after the loop.
// Masked q-row (qsel=0): p == 1 for all k -> O/l = mean(V), matching reference.
__launch_bounds__(256, 3)
__global__ void attn_kernel(const u16* __restrict__ qg, const u16* __restrict__ kg,
                            const u16* __restrict__ vtg, const float* __restrict__ madd,
                            u16* __restrict__ attn_out) {
  __shared__ u16 lK[128 * 64];   // [k_local][d], 128B rows, XOR key = row&7
  __shared__ u16 lV[64 * 128];   // [d][k_local], 256B rows, XOR key = row&15

  // bijective XCD swizzle: 768 blocks, 96 per XCD
  int bid = blockIdx.y * 64 + blockIdx.x;
  int orig = (bid & 7) * 96 + (bid >> 3);
  int qb = orig & 63, bh = orig >> 6;

  int b = bh / HEADS, hd = bh - b * HEADS;
  int q0 = qb * 64;
  int tid = threadIdx.x;
  int w = tid >> 6, lane = tid & 63;
  int l15 = lane & 15, lg = lane >> 4;
  int r_in = lane >> 3, jblk = (lane & 7) ^ r_in;

  const u16* Q = qg + (size_t)bh * NSEQ * 64;
  const u16* K = kg + (size_t)bh * NSEQ * 64;
  const u16* VT = vtg + (size_t)bh * 64 * NSEQ;
  const float* marow = madd + b * NSEQ;

  int qrow = q0 + w * 16 + l15;
  short8 qf[2];
#pragma unroll
  for (int hf = 0; hf < 2; ++hf)
    qf[hf] = *(const short8*)(Q + (size_t)qrow * 64 + hf * 32 + lg * 8);

  float aqf = marow[qrow];                       // 0 or -FLT_MAX
  float qsel = (aqf == 0.0f) ? 1.0f : 0.0f;      // lane-uniform q-mask flag
  float scq = SC2 * qsel;

  // lane-constant swizzled read offsets
  int swk = (l15 & 7) << 4;
  int offKA = l15 * 128 + ((lg * 16) ^ swk);
  int offKB = l15 * 128 + (((4 + lg) * 16) ^ swk);
  int voff[4];
#pragma unroll
  for (int c = 0; c < 4; ++c)
    voff[c] = l15 * 256 + ((((c * 4 + lg) ^ l15)) << 4);

  f32x4 acc[4];  // O^T: acc[ds][r] = O[d = ds*16 + lg*4 + r][q = qrow]
#pragma unroll
  for (int ds_ = 0; ds_ < 4; ++ds_) acc[ds_] = (f32x4){0.f, 0.f, 0.f, 0.f};
  f32x4 lsum = (f32x4){0.f, 0.f, 0.f, 0.f};      // per-lane partial softmax denom

  // STAGE via global_load_lds, linear dest + per-lane pre-swizzled source (R5-proven)
#define STAGE(k0s)                                                                    \
  {                                                                                   \
    _Pragma("unroll")                                                                 \
    for (int c = 0; c < 4; ++c) {                                                     \
      int krb = w * 32 + c * 8;                                                       \
      gload_lds16(K + (size_t)((k0s) + krb + r_in) * 64 + jblk * 8, &lK[krb * 64]);   \
      int vrb = w * 16 + c * 4;                                                       \
      int vsb = l15 ^ (c * 4 + lg);                                                   \
      gload_lds16(VT + (size_t)(vrb + lg) * NSEQ + (k0s) + vsb * 8, &lV[vrb * 128]);  \
    }                                                                                 \
  }

  STAGE(0);
  asm volatile("s_waitcnt vmcnt(0)" ::: "memory");
  __syncthreads();

  const int NT = NSEQ / 128;
  for (int t = 0; t < NT; ++t) {
    int k0 = t * 128;

    // S^T = K Q^T : p[cs][r] = S[q = qrow][k = k0 + cs*16 + lg*4 + r]
    f32x4 p[8];
    __builtin_amdgcn_s_setprio(1);
#pragma unroll
    for (int cs = 0; cs < 8; ++cs) {
      short8 kf0 = *(const short8*)((const char*)lK + offKA + cs * 2048);
      short8 kf1 = *(const short8*)((const char*)lK + offKB + cs * 2048);
      f32x4 z = (f32x4){0.f, 0.f, 0.f, 0.f};
      z = __builtin_amdgcn_mfma_f32_16x16x32_bf16(kf0, qf[0], z, 0, 0, 0);
      p[cs] = __builtin_amdgcn_mfma_f32_16x16x32_bf16(kf1, qf[1], z, 0, 0, 0);
    }
    __builtin_amdgcn_s_setprio(0);

    // streaming softmax: p = exp2(s*scq + mf*qsel); accumulate partial l
#pragma unroll
    for (int cs = 0; cs < 8; ++cs) {
      f32x4 mf = *(const f32x4*)(marow + k0 + cs * 16 + lg * 4);
      f32x4 d = p[cs] * scq + mf * qsel;
#pragma unroll
      for (int r = 0; r < 4; ++r) p[cs][r] = EXP2(d[r]);
    }
    lsum += ((p[0] + p[1]) + (p[2] + p[3])) + ((p[4] + p[5]) + (p[6] + p[7]));

    // P^T -> bf16 packed words
    uint32_t wd[8][2];
#pragma unroll
    for (int cs = 0; cs < 8; ++cs)
#pragma unroll
      for (int hh = 0; hh < 2; ++hh)
        asm("v_cvt_pk_bf16_f32 %0, %1, %2" : "=v"(wd[cs][hh]) : "v"(p[cs][2 * hh]), "v"(p[cs][2 * hh + 1]));

    // permlane dance -> PV B-operand fragments (4 chunks of 32 k)
    short8 pf[4];
#pragma unroll
    for (int c = 0; c < 4; ++c) {
      union { uint32_t u[4]; short8 s8; } cv;
#pragma unroll
      for (int hh = 0; hh < 2; ++hh) {
        uint32_t A = wd[2 * c][hh], B = wd[2 * c + 1][hh];
        asm("v_permlane32_swap_b32 %0, %1" : "+v"(A), "+v"(B));
        asm("v_permlane16_swap_b32 %0, %1" : "+v"(A), "+v"(B));
        cv.u[hh] = A;
        cv.u[2 + hh] = B;
      }
      pf[c] = cv.s8;
    }

    // O^T += V^T P^T  (reduction over 128 k in 4 chunks)
    __builtin_amdgcn_s_setprio(1);
#pragma unroll
    for (int ds_ = 0; ds_ < 4; ++ds_) {
#pragma unroll
      for (int c = 0; c < 4; ++c) {
        short8 vf = *(const short8*)((const char*)lV + voff[c] + ds_ * 4096);
        acc[ds_] = __builtin_amdgcn_mfma_f32_16x16x32_bf16(vf, pf[c], acc[ds_], 0, 0, 0);
      }
    }
    __builtin_amdgcn_s_setprio(0);

    __syncthreads();                  // all waves done reading tile t
    if (t + 1 < NT) {
      STAGE(k0 + 128);                // refill same buffer
      asm volatile("s_waitcnt vmcnt(0)" ::: "memory");
      __syncthreads();
    }
  }

  // one-time l reduction: in-lane 4 -> cross-lane-group (xor16, xor32)
  float rsum = (lsum[0] + lsum[1]) + (lsum[2] + lsum[3]);
  rsum += __shfl_xor(rsum, 16);
  rsum += __shfl_xor(rsum, 32);

  // epilogue: attn_out[b, n=qrow, hd*64 + d] = O^T[d][qrow] / l
  float inv = 1.0f / rsum;
  size_t base = ((size_t)b * NSEQ + qrow) * 384 + hd * 64;
#pragma unroll
  for (int ds_ = 0; ds_ < 4; ++ds_) {
    uint32_t w0, w1;
    float a0 = acc[ds_][0] * inv, a1 = acc[ds_][1] * inv;
    float a2 = acc[ds_][2] * inv, a3 = acc[ds_][3] * inv;
    asm("v_cvt_pk_bf16_f32 %0, %1, %2" : "=v"(w0) : "v"(a0), "v"(a1));
    asm("v_cvt_pk_bf16_f32 %0, %1, %2" : "=v"(w1) : "v"(a2), "v"(a3));
    uint2 st; st.x = w0; st.y = w1;
    *(uint2*)(attn_out + base + ds_ * 16 + lg * 4) = st;
  }
#undef STAGE
}

extern "C" void kernel_launch(void* const* d_in, const int* in_sizes, int n_in,
                              void* d_out, int out_size, void* d_ws, size_t ws_size,
                              hipStream_t stream) {
  const float* x = (const float*)d_in[0];
  const int* mask = (const int*)d_in[1];
  const float* w_qkv = (const float*)d_in[2];
  const float* w_proj = (const float*)d_in[3];
  const float* b_proj = (const float*)d_in[4];
  float* out = (float*)d_out;

  char* ws = (char*)d_ws;
  u16* x_bf = (u16*)(ws + 0);              //  8192x384
  u16* wqkv_bf = (u16*)(ws + 6291456);     //  1152x384
  u16* wproj_bf = (u16*)(ws + 7176192);    //   384x384
  u16* q_bf = (u16*)(ws + 7471104);        //  [b,h,n,d]
  u16* k_bf = (u16*)(ws + 13762560);       //  [b,h,n,d]
  u16* vt_bf = (u16*)(ws + 20054016);      //  [b,h,d,n]
  u16* attn_bf = (u16*)(ws + 26345472);    //  8192x384
  float* madd = (float*)(ws + 32636928);   //  [2][4096] f32

  // fused prep: 3 casts + mask addend
  const int NPREP = 3145728 / 8 + 442368 / 8 + 147456 / 8 + 2 * NSEQ;
  prep_kernel<<<(NPREP + 255) / 256, 256, 0, stream>>>(x, w_qkv, w_proj, mask,
                                                       x_bf, wqkv_bf, wproj_bf, madd);

  gemm_bt<0><<<dim3(64, 9), 256, 0, stream>>>(x_bf, wqkv_bf, 384, 1152,
                                              q_bf, k_bf, vt_bf, nullptr, nullptr);
  attn_kernel<<<dim3(64, 12), 256, 0, stream>>>(q_bf, k_bf, vt_bf, madd, attn_bf);
  gemm_bt<1><<<dim3(64, 3), 256, 0, stream>>>(attn_bf, wproj_bf, 384, 384,
                                              nullptr, nullptr, nullptr, b_proj, out);
}

// Round 11
// 132.038 us; speedup vs baseline: 3.0593x; 1.0372x over previous
//
#include <hip/hip_runtime.h>
#include <cfloat>
#include <cstdint>
#include <cstddef>

using u16 = unsigned short;
typedef __attribute__((ext_vector_type(8))) short short8;
typedef __attribute__((ext_vector_type(4))) float f32x4;

#define HEADS 6
#define NSEQ 4096
#define SCALEF 0.125f
#define LOG2E 1.4426950408889634f
#define SC2 (SCALEF * LOG2E)

#if __has_builtin(__builtin_amdgcn_exp2f)
#define EXP2(x) __builtin_amdgcn_exp2f(x)
#else
#define EXP2(x) exp2f(x)
#endif

__device__ __forceinline__ u16 f2bf_rn(float f) {
  unsigned int u = __builtin_bit_cast(unsigned int, f);
  u = (u + 0x7FFFu + ((u >> 16) & 1u)) >> 16;
  return (u16)u;
}

__device__ __forceinline__ void gload_lds16(const void* g, void* l) {
  __builtin_amdgcn_global_load_lds((const __attribute__((address_space(1))) void*)g,
                                   (__attribute__((address_space(3))) void*)l, 16, 0, 0);
}

// Swizzled b128 read from a [rows][64] u16 LDS tile (128B rows). (GEMM use)
__device__ __forceinline__ short8 frag_read(const u16* tile, int row, int blk) {
  int byt = row * 128 + ((blk * 16) ^ ((row & 7) << 4));
  return *(const short8*)((const char*)tile + byt);
}

__device__ __forceinline__ void cast8(const float* __restrict__ s, u16* __restrict__ d, int i) {
  const float4* sp = (const float4*)s;
  float4 a = sp[2 * i], b = sp[2 * i + 1];
  short8 r;
  r[0] = (short)f2bf_rn(a.x); r[1] = (short)f2bf_rn(a.y);
  r[2] = (short)f2bf_rn(a.z); r[3] = (short)f2bf_rn(a.w);
  r[4] = (short)f2bf_rn(b.x); r[5] = (short)f2bf_rn(b.y);
  r[6] = (short)f2bf_rn(b.z); r[7] = (short)f2bf_rn(b.w);
  ((short8*)d)[i] = r;
}

// fused prep: cast x / w_qkv / w_proj to bf16 + mask -> float addend
__global__ void prep_kernel(const float* __restrict__ x, const float* __restrict__ wqkv,
                            const float* __restrict__ wproj, const int* __restrict__ mask,
                            u16* __restrict__ xb, u16* __restrict__ wqb, u16* __restrict__ wpb,
                            float* __restrict__ madd) {
  const int NX = 3145728 / 8, NQ = 442368 / 8, NP = 147456 / 8;
  int i = blockIdx.x * blockDim.x + threadIdx.x;
  if (i < NX) cast8(x, xb, i);
  else if (i < NX + NQ) cast8(wqkv, wqb, i - NX);
  else if (i < NX + NQ + NP) cast8(wproj, wpb, i - NX - NQ);
  else {
    int j = i - (NX + NQ + NP);
    if (j < 2 * NSEQ) madd[j] = mask[j] ? 0.f : -FLT_MAX;
  }
}

// C = A(MxK) * B(NxK)^T ; 128x128 tile, BK=64, 4 waves (2x2 of 64x64).
template <int EPI>
__launch_bounds__(256)
__global__ void gemm_bt(const u16* __restrict__ A, const u16* __restrict__ B,
                        int Kdim, int Ndim,
                        u16* __restrict__ q_out, u16* __restrict__ k_out, u16* __restrict__ vt_out,
                        const float* __restrict__ bias, float* __restrict__ out) {
  __shared__ u16 lA[128 * 64];
  __shared__ u16 lB[128 * 64];
  int brow = blockIdx.x, bcol = blockIdx.y;
  int tid = threadIdx.x;
  int w = tid >> 6, lane = tid & 63;
  int wr = w >> 1, wc = w & 1;
  int r_in = lane >> 3;
  int jblk = (lane & 7) ^ r_in;
  int l15 = lane & 15, lg = lane >> 4;

  f32x4 acc[4][4];
#pragma unroll
  for (int i = 0; i < 4; i++)
#pragma unroll
    for (int j = 0; j < 4; j++) acc[i][j] = (f32x4){0.f, 0.f, 0.f, 0.f};

  const u16* Ab = A + (size_t)(brow * 128 + w * 32 + r_in) * Kdim + jblk * 8;
  const u16* Bb = B + (size_t)(bcol * 128 + w * 32 + r_in) * Kdim + jblk * 8;

  int ksteps = Kdim >> 6;
  for (int kt = 0; kt < ksteps; ++kt) {
    __syncthreads();
#pragma unroll
    for (int c = 0; c < 4; ++c) {
      gload_lds16(Ab + kt * 64 + (size_t)(c * 8) * Kdim, &lA[(w * 32 + c * 8) * 64]);
      gload_lds16(Bb + kt * 64 + (size_t)(c * 8) * Kdim, &lB[(w * 32 + c * 8) * 64]);
    }
    asm volatile("s_waitcnt vmcnt(0)" ::: "memory");
    __syncthreads();

    short8 af[4][2], bfr[4][2];
#pragma unroll
    for (int ms = 0; ms < 4; ++ms)
#pragma unroll
      for (int hf = 0; hf < 2; ++hf)
        af[ms][hf] = frag_read(lA, wr * 64 + ms * 16 + l15, hf * 4 + lg);
#pragma unroll
    for (int ns = 0; ns < 4; ++ns)
#pragma unroll
      for (int hf = 0; hf < 2; ++hf)
        bfr[ns][hf] = frag_read(lB, wc * 64 + ns * 16 + l15, hf * 4 + lg);
#pragma unroll
    for (int ms = 0; ms < 4; ++ms)
#pragma unroll
      for (int ns = 0; ns < 4; ++ns) {
        acc[ms][ns] = __builtin_amdgcn_mfma_f32_16x16x32_bf16(af[ms][0], bfr[ns][0], acc[ms][ns], 0, 0, 0);
        acc[ms][ns] = __builtin_amdgcn_mfma_f32_16x16x32_bf16(af[ms][1], bfr[ns][1], acc[ms][ns], 0, 0, 0);
      }
  }

#pragma unroll
  for (int ms = 0; ms < 4; ++ms)
#pragma unroll
    for (int ns = 0; ns < 4; ++ns)
#pragma unroll
      for (int r = 0; r < 4; ++r) {
        int row_g = brow * 128 + wr * 64 + ms * 16 + lg * 4 + r;
        int col_g = bcol * 128 + wc * 64 + ns * 16 + l15;
        float v = acc[ms][ns][r];
        if (EPI == 0) {
          int t = col_g / 384;
          int rem = col_g - t * 384;
          int h = rem >> 6, d = rem & 63;
          int b = row_g >> 12, n = row_g & 4095;
          u16 val = f2bf_rn(v);
          size_t bh = (size_t)(b * HEADS + h);
          if (t == 0)      q_out[(bh * NSEQ + n) * 64 + d] = val;
          else if (t == 1) k_out[(bh * NSEQ + n) * 64 + d] = val;
          else             vt_out[(bh * 64 + d) * NSEQ + n] = val;
        } else {
          out[(size_t)row_g * Ndim + col_g] = v + bias[col_g];
        }
      }
}

// Flash attention, swapped-operand, KT=128, single 32KB buffer, streaming softmax
// (R10-proven core). SPLIT=1: k-range split across 2x grid; each block writes
// f32 partial (O, l); exact because streaming softmax has no max state.
template <int SPLIT>
__launch_bounds__(256, 3)
__global__ void attn_kernel(const u16* __restrict__ qg, const u16* __restrict__ kg,
                            const u16* __restrict__ vtg, const float* __restrict__ madd,
                            u16* __restrict__ attn_out,
                            float* __restrict__ o_part, float* __restrict__ l_part) {
  __shared__ u16 lK[128 * 64];   // [k_local][d], 128B rows, XOR key = row&7
  __shared__ u16 lV[64 * 128];   // [d][k_local], 256B rows, XOR key = row&15

  int bid = blockIdx.y * 64 + blockIdx.x;
  int qb, bh, kh, kbase, NT;
  if (SPLIT) {
    // bijective XCD swizzle: 1536 blocks, 192 per XCD; 3 (bh,kh) combos/XCD
    int orig = (bid & 7) * 192 + (bid >> 3);
    qb = orig & 63;
    int rr = orig >> 6;            // 0..23
    bh = rr % 12;
    kh = rr / 12;
    kbase = kh * (NSEQ / 2);
    NT = (NSEQ / 2) / 128;         // 16
  } else {
    int orig = (bid & 7) * 96 + (bid >> 3);
    qb = orig & 63;
    bh = orig >> 6;
    kh = 0;
    kbase = 0;
    NT = NSEQ / 128;               // 32
  }

  int b = bh / HEADS, hd = bh - b * HEADS;
  int q0 = qb * 64;
  int tid = threadIdx.x;
  int w = tid >> 6, lane = tid & 63;
  int l15 = lane & 15, lg = lane >> 4;
  int r_in = lane >> 3, jblk = (lane & 7) ^ r_in;

  const u16* Q = qg + (size_t)bh * NSEQ * 64;
  const u16* K = kg + (size_t)bh * NSEQ * 64;
  const u16* VT = vtg + (size_t)bh * 64 * NSEQ;
  const float* marow = madd + b * NSEQ;

  int qrow = q0 + w * 16 + l15;
  short8 qf[2];
#pragma unroll
  for (int hf = 0; hf < 2; ++hf)
    qf[hf] = *(const short8*)(Q + (size_t)qrow * 64 + hf * 32 + lg * 8);

  float aqf = marow[qrow];                       // 0 or -FLT_MAX
  float qsel = (aqf == 0.0f) ? 1.0f : 0.0f;      // lane-uniform q-mask flag
  float scq = SC2 * qsel;

  // lane-constant swizzled read offsets
  int swk = (l15 & 7) << 4;
  int offKA = l15 * 128 + ((lg * 16) ^ swk);
  int offKB = l15 * 128 + (((4 + lg) * 16) ^ swk);
  int voff[4];
#pragma unroll
  for (int c = 0; c < 4; ++c)
    voff[c] = l15 * 256 + ((((c * 4 + lg) ^ l15)) << 4);

  f32x4 acc[4];  // O^T: acc[ds][r] = O[d = ds*16 + lg*4 + r][q = qrow]
#pragma unroll
  for (int ds_ = 0; ds_ < 4; ++ds_) acc[ds_] = (f32x4){0.f, 0.f, 0.f, 0.f};
  f32x4 lsum = (f32x4){0.f, 0.f, 0.f, 0.f};      // per-lane partial softmax denom

  // STAGE via global_load_lds, linear dest + per-lane pre-swizzled source (R5-proven)
#define STAGE(k0s)                                                                    \
  {                                                                                   \
    _Pragma("unroll")                                                                 \
    for (int c = 0; c < 4; ++c) {                                                     \
      int krb = w * 32 + c * 8;                                                       \
      gload_lds16(K + (size_t)((k0s) + krb + r_in) * 64 + jblk * 8, &lK[krb * 64]);   \
      int vrb = w * 16 + c * 4;                                                       \
      int vsb = l15 ^ (c * 4 + lg);                                                   \
      gload_lds16(VT + (size_t)(vrb + lg) * NSEQ + (k0s) + vsb * 8, &lV[vrb * 128]);  \
    }                                                                                 \
  }

  STAGE(kbase);
  asm volatile("s_waitcnt vmcnt(0)" ::: "memory");
  __syncthreads();

  for (int t = 0; t < NT; ++t) {
    int k0 = kbase + t * 128;

    // S^T = K Q^T : p[cs][r] = S[q = qrow][k = k0 + cs*16 + lg*4 + r]
    f32x4 p[8];
    __builtin_amdgcn_s_setprio(1);
#pragma unroll
    for (int cs = 0; cs < 8; ++cs) {
      short8 kf0 = *(const short8*)((const char*)lK + offKA + cs * 2048);
      short8 kf1 = *(const short8*)((const char*)lK + offKB + cs * 2048);
      f32x4 z = (f32x4){0.f, 0.f, 0.f, 0.f};
      z = __builtin_amdgcn_mfma_f32_16x16x32_bf16(kf0, qf[0], z, 0, 0, 0);
      p[cs] = __builtin_amdgcn_mfma_f32_16x16x32_bf16(kf1, qf[1], z, 0, 0, 0);
    }
    __builtin_amdgcn_s_setprio(0);

    // streaming softmax: p = exp2(s*scq + mf*qsel); accumulate partial l
#pragma unroll
    for (int cs = 0; cs < 8; ++cs) {
      f32x4 mf = *(const f32x4*)(marow + k0 + cs * 16 + lg * 4);
      f32x4 d = p[cs] * scq + mf * qsel;
#pragma unroll
      for (int r = 0; r < 4; ++r) p[cs][r] = EXP2(d[r]);
    }
    lsum += ((p[0] + p[1]) + (p[2] + p[3])) + ((p[4] + p[5]) + (p[6] + p[7]));

    // P^T -> bf16 packed words
    uint32_t wd[8][2];
#pragma unroll
    for (int cs = 0; cs < 8; ++cs)
#pragma unroll
      for (int hh = 0; hh < 2; ++hh)
        asm("v_cvt_pk_bf16_f32 %0, %1, %2" : "=v"(wd[cs][hh]) : "v"(p[cs][2 * hh]), "v"(p[cs][2 * hh + 1]));

    // permlane dance -> PV B-operand fragments (4 chunks of 32 k)
    short8 pf[4];
#pragma unroll
    for (int c = 0; c < 4; ++c) {
      union { uint32_t u[4]; short8 s8; } cv;
#pragma unroll
      for (int hh = 0; hh < 2; ++hh) {
        uint32_t A = wd[2 * c][hh], B = wd[2 * c + 1][hh];
        asm("v_permlane32_swap_b32 %0, %1" : "+v"(A), "+v"(B));
        asm("v_permlane16_swap_b32 %0, %1" : "+v"(A), "+v"(B));
        cv.u[hh] = A;
        cv.u[2 + hh] = B;
      }
      pf[c] = cv.s8;
    }

    // O^T += V^T P^T  (reduction over 128 k in 4 chunks)
    __builtin_amdgcn_s_setprio(1);
#pragma unroll
    for (int ds_ = 0; ds_ < 4; ++ds_) {
#pragma unroll
      for (int c = 0; c < 4; ++c) {
        short8 vf = *(const short8*)((const char*)lV + voff[c] + ds_ * 4096);
        acc[ds_] = __builtin_amdgcn_mfma_f32_16x16x32_bf16(vf, pf[c], acc[ds_], 0, 0, 0);
      }
    }
    __builtin_amdgcn_s_setprio(0);

    __syncthreads();                  // all waves done reading tile t
    if (t + 1 < NT) {
      STAGE(k0 + 128);                // refill same buffer
      asm volatile("s_waitcnt vmcnt(0)" ::: "memory");
      __syncthreads();
    }
  }

  // one-time l reduction: in-lane 4 -> cross-lane-group (xor16, xor32)
  float rsum = (lsum[0] + lsum[1]) + (lsum[2] + lsum[3]);
  rsum += __shfl_xor(rsum, 16);
  rsum += __shfl_xor(rsum, 32);

  size_t base = ((size_t)b * NSEQ + qrow) * 384 + hd * 64;
  if (SPLIT) {
    // write f32 partials; combine kernel finishes (O0+O1)/(l0+l1)
    float* op = o_part + (size_t)kh * (8192ull * 384);
#pragma unroll
    for (int ds_ = 0; ds_ < 4; ++ds_)
      *(f32x4*)(op + base + ds_ * 16 + lg * 4) = acc[ds_];
    if (lg == 0)
      l_part[(kh * 12 + bh) * NSEQ + qrow] = rsum;
  } else {
    float inv = 1.0f / rsum;
#pragma unroll
    for (int ds_ = 0; ds_ < 4; ++ds_) {
      uint32_t w0, w1;
      float a0 = acc[ds_][0] * inv, a1 = acc[ds_][1] * inv;
      float a2 = acc[ds_][2] * inv, a3 = acc[ds_][3] * inv;
      asm("v_cvt_pk_bf16_f32 %0, %1, %2" : "=v"(w0) : "v"(a0), "v"(a1));
      asm("v_cvt_pk_bf16_f32 %0, %1, %2" : "=v"(w1) : "v"(a2), "v"(a3));
      uint2 st; st.x = w0; st.y = w1;
      *(uint2*)(attn_out + base + ds_ * 16 + lg * 4) = st;
    }
  }
#undef STAGE
}

// combine k-half partials: out = (O0 + O1) / (l0 + l1), cast bf16
__global__ void combine_kernel(const float* __restrict__ o_part, const float* __restrict__ l_part,
                               u16* __restrict__ out) {
  int i = blockIdx.x * blockDim.x + threadIdx.x;   // float4 index, 786432 total
  const float4* O0 = (const float4*)o_part;
  const float4* O1 = (const float4*)(o_part + 8192ull * 384);
  float4 a = O0[i], c = O1[i];
  int elem = i * 4;
  int ng = elem / 384;
  int cc = elem - ng * 384;
  int h = cc >> 6;
  int b = ng >> 12, n = ng & 4095;
  int li = (b * HEADS + h) * NSEQ + n;
  float inv = 1.0f / (l_part[li] + l_part[12 * NSEQ + li]);
  float a0 = (a.x + c.x) * inv, a1 = (a.y + c.y) * inv;
  float a2 = (a.z + c.z) * inv, a3 = (a.w + c.w) * inv;
  uint32_t w0, w1;
  asm("v_cvt_pk_bf16_f32 %0, %1, %2" : "=v"(w0) : "v"(a0), "v"(a1));
  asm("v_cvt_pk_bf16_f32 %0, %1, %2" : "=v"(w1) : "v"(a2), "v"(a3));
  uint2 st; st.x = w0; st.y = w1;
  *(uint2*)(out + elem) = st;
}

extern "C" void kernel_launch(void* const* d_in, const int* in_sizes, int n_in,
                              void* d_out, int out_size, void* d_ws, size_t ws_size,
                              hipStream_t stream) {
  const float* x = (const float*)d_in[0];
  const int* mask = (const int*)d_in[1];
  const float* w_qkv = (const float*)d_in[2];
  const float* w_proj = (const float*)d_in[3];
  const float* b_proj = (const float*)d_in[4];
  float* out = (float*)d_out;

  char* ws = (char*)d_ws;
  u16* x_bf = (u16*)(ws + 0);              //  8192x384
  u16* wqkv_bf = (u16*)(ws + 6291456);     //  1152x384
  u16* wproj_bf = (u16*)(ws + 7176192);    //   384x384
  u16* q_bf = (u16*)(ws + 7471104);        //  [b,h,n,d]
  u16* k_bf = (u16*)(ws + 13762560);       //  [b,h,n,d]
  u16* vt_bf = (u16*)(ws + 20054016);      //  [b,h,d,n]
  u16* attn_bf = (u16*)(ws + 26345472);    //  8192x384
  float* madd = (float*)(ws + 32636928);   //  [2][4096] f32, ends 32669696
  float* o_part = (float*)(ws + 32669696); //  2 x 8192x384 f32 = 25165824
  float* l_part = (float*)(ws + 57835520); //  2 x 12x4096 f32 = 393216; ends 58228736

  // fused prep: 3 casts + mask addend
  const int NPREP = 3145728 / 8 + 442368 / 8 + 147456 / 8 + 2 * NSEQ;
  prep_kernel<<<(NPREP + 255) / 256, 256, 0, stream>>>(x, w_qkv, w_proj, mask,
                                                       x_bf, wqkv_bf, wproj_bf, madd);

  gemm_bt<0><<<dim3(64, 9), 256, 0, stream>>>(x_bf, wqkv_bf, 384, 1152,
                                              q_bf, k_bf, vt_bf, nullptr, nullptr);

  if (ws_size >= 58228736) {
    attn_kernel<1><<<dim3(64, 24), 256, 0, stream>>>(q_bf, k_bf, vt_bf, madd,
                                                     nullptr, o_part, l_part);
    combine_kernel<<<3072, 256, 0, stream>>>(o_part, l_part, attn_bf);
  } else {
    attn_kernel<0><<<dim3(64, 12), 256, 0, stream>>>(q_bf, k_bf, vt_bf, madd,
                                                     attn_bf, nullptr, nullptr);
  }

  gemm_bt<1><<<dim3(64, 3), 256, 0, stream>>>(attn_bf, wproj_bf, 384, 384,
                                              nullptr, nullptr, nullptr, b_proj, out);
}